// Round 4
// baseline (120.114 us; speedup 1.0000x reference)
//
#include <hip/hip_runtime.h>
#include <math.h>

// SSIM loss, round 4: both separable blurs on the matrix cores.
//   h-blur: C[row][outcol] = prod[row][k] * Bh[k][outcol], Bh = 11-band.
//   v-blur: C2[outrow][q*32+col] = Wv[outrow][k] * S[k][q*32+col].
// f16 inputs, f32 MFMA accumulate. Tile 32x32, IH=48 (3 m-tiles), K=64.
// LDS: raw x/y f32 [48][68] + S f16 col-major [160][72] + w-table = 49.2 KB
// -> 3 blocks/CU. XCD-bijective block swizzle for halo L2 reuse.
// Verified layouts (guide m89/m92): A/B frag: lane&15 = m/n, k = 8*(lane>>4)+j
// (8 contiguous k per lane); C/D: col = lane&15, row = 4*(lane>>4)+reg.

typedef _Float16 f16x8 __attribute__((ext_vector_type(8)));
typedef _Float16 f16x4 __attribute__((ext_vector_type(4)));
typedef float f32x4 __attribute__((ext_vector_type(4)));

#define NPIX (16 * 3 * 512 * 512)
#define NBLOCKS 12288            // 48 planes * 16*16 tiles of 32x32

#define RAW_PITCH 68             // f32 per raw row (64 + 4 pad; 68%32=4 -> 2-way)
#define RAW_ROWS 48
#define S_PITCH 72               // f16 per S row (64 + 8 pad; 36 words %32=4)
#define S_ROWS 160               // n = q*32 + col
#define RAW_BYTES (RAW_ROWS * RAW_PITCH * 4)   // 13056
#define S_OFF (2 * RAW_BYTES)                  // 26112
#define S_BYTES (S_ROWS * S_PITCH * 2)         // 23040
#define WTAB_OFF (S_OFF + S_BYTES)             // 49152 (16 f16 = 32 B)
#define RED_OFF (WTAB_OFF + 32)
#define SMEM_BYTES (RED_OFF + 16)              // 49200

__global__ __launch_bounds__(256, 3) void ssim_main(
    const float* __restrict__ X, const float* __restrict__ Y,
    float* __restrict__ partial)
{
    static const float GWF[11] = {
        0.00102838f, 0.00759876f, 0.03600026f, 0.10936083f, 0.21300567f,
        0.26601190f, 0.21300567f, 0.10936083f, 0.03600026f, 0.00759876f,
        0.00102838f};

    __shared__ __align__(16) char smem[SMEM_BYTES];
    float*     rawx = (float*)smem;
    float*     rawy = (float*)(smem + RAW_BYTES);
    _Float16*  Sh   = (_Float16*)(smem + S_OFF);
    _Float16*  wtab = (_Float16*)(smem + WTAB_OFF);
    float*     red  = (float*)(smem + RED_OFF);

    const int tid = threadIdx.x;

    // XCD-bijective swizzle (NBLOCKS % 8 == 0): each XCD gets 6 whole planes.
    const int wg    = (blockIdx.x & 7) * (NBLOCKS / 8) + (blockIdx.x >> 3);
    const int plane = wg >> 8;          // 256 tiles per plane
    const int t     = wg & 255;
    const int tr    = t >> 4;           // 16 row-tiles
    const int tc    = t & 15;           // 16 col-tiles

    const float* xp = X + (size_t)plane * (512 * 512);
    const float* yp = Y + (size_t)plane * (512 * 512);
    const int row0 = tr * 32 - 5;       // global row of raw row 0
    const int colT = tc * 32;           // global col of output col 0
                                        // raw col k <-> global col colT-8+k

    // ---- stage raw x,y tiles (48 x 64 f32), w-table, zero S tail ----
    if (tid < 16)
        wtab[tid] = (tid >= 1 && tid <= 11) ? (_Float16)GWF[tid - 1]
                                            : (_Float16)0.0f;
    {
        unsigned int* S32 = (unsigned int*)Sh;   // zero S k in [48,64)
        for (int i = tid; i < S_ROWS * 8; i += 256)
            S32[(i >> 3) * (S_PITCH / 2) + 24 + (i & 7)] = 0u;
    }
    for (int u = tid; u < 1536; u += 256) {      // 48 rows * 16 quads * 2 tsr
        const int row  = u >> 5;
        const int v    = u & 31;
        const int tsr  = v >> 4;
        const int quad = v & 15;
        const int grow = row0 + row;
        const int gcol = colT - 8 + quad * 4;
        float4 val = make_float4(0.f, 0.f, 0.f, 0.f);
        if ((unsigned)grow < 512u && (unsigned)gcol <= 508u) {
            const float* src = (tsr ? yp : xp) + grow * 512 + gcol;
            val = *(const float4*)src;
        }
        float* dst = (tsr ? rawy : rawx) + row * RAW_PITCH + quad * 4;
        *(float4*)dst = val;
    }
    __syncthreads();

    const int w   = tid >> 6;
    const int lane = tid & 63;
    const int l15 = lane & 15;
    const int kg  = lane >> 4;

    // ---- build Bh band fragments: Bh[k][n] = w[k-n-3] ----
    f16x8 BH[2][2];
#pragma unroll
    for (int kt = 0; kt < 2; ++kt)
#pragma unroll
        for (int nt = 0; nt < 2; ++nt)
#pragma unroll
            for (int j = 0; j < 8; ++j) {
                const int k = kt * 32 + kg * 8 + j;
                const int n = nt * 16 + l15;
                int idx = k - n - 2;             // w-index + 1
                idx = idx < 0 ? 0 : (idx > 15 ? 15 : idx);
                BH[kt][nt][j] = wtab[idx];
            }

    // ---- h-blur: 15 m-tiles (q=0..4 x rtile=0..2), wave w owns mi=w,w+4,.. --
    const f32x4 zero4 = {0.f, 0.f, 0.f, 0.f};
    f32x4 acc[4][2];
#pragma unroll
    for (int ti = 0; ti < 4; ++ti) { acc[ti][0] = zero4; acc[ti][1] = zero4; }

#pragma unroll
    for (int ti = 0; ti < 4; ++ti) {
        const int mi = w + ti * 4;
        if (mi < 15) {
            const int q  = mi / 3;
            const int rt = mi - q * 3;
            const int row = rt * 16 + l15;
#pragma unroll
            for (int kt = 0; kt < 2; ++kt) {
                const int koff = kt * 32 + kg * 8;
                f16x8 frag;
                const float* px = rawx + row * RAW_PITCH + koff;
                const float* py = rawy + row * RAW_PITCH + koff;
                if (q == 0 || q == 2 || q == 4) {
                    float4 a = *(const float4*)px, b = *(const float4*)(px + 4);
                    f16x8 hx = {(_Float16)a.x, (_Float16)a.y, (_Float16)a.z,
                                (_Float16)a.w, (_Float16)b.x, (_Float16)b.y,
                                (_Float16)b.z, (_Float16)b.w};
                    if (q == 0) frag = hx;
                    else if (q == 2) frag = hx * hx;
                    else {
                        float4 c = *(const float4*)py, d = *(const float4*)(py + 4);
                        f16x8 hy = {(_Float16)c.x, (_Float16)c.y, (_Float16)c.z,
                                    (_Float16)c.w, (_Float16)d.x, (_Float16)d.y,
                                    (_Float16)d.z, (_Float16)d.w};
                        frag = hx * hy;
                    }
                } else {
                    float4 c = *(const float4*)py, d = *(const float4*)(py + 4);
                    f16x8 hy = {(_Float16)c.x, (_Float16)c.y, (_Float16)c.z,
                                (_Float16)c.w, (_Float16)d.x, (_Float16)d.y,
                                (_Float16)d.z, (_Float16)d.w};
                    frag = (q == 1) ? hy : hy * hy;
                }
#pragma unroll
                for (int nt = 0; nt < 2; ++nt)
                    acc[ti][nt] = __builtin_amdgcn_mfma_f32_16x16x32_f16(
                        frag, BH[kt][nt], acc[ti][nt], 0, 0, 0);
            }
            // write C -> S (col-major [n][k]); lane has col n, rows hr0..hr0+3
            const int hr0 = rt * 16 + kg * 4;
#pragma unroll
            for (int nt = 0; nt < 2; ++nt) {
                const int n = q * 32 + nt * 16 + l15;
                f16x4 h = {(_Float16)acc[ti][nt][0], (_Float16)acc[ti][nt][1],
                           (_Float16)acc[ti][nt][2], (_Float16)acc[ti][nt][3]};
                *(f16x4*)(Sh + n * S_PITCH + hr0) = h;
            }
        }
    }
    __syncthreads();

    // ---- v-blur: wave w -> (mt = w&1, colhalf = w>>1) ----
    const int mt = w & 1;
    const int ch = w >> 1;
    f16x8 WV[2];
#pragma unroll
    for (int kt = 0; kt < 2; ++kt)
#pragma unroll
        for (int j = 0; j < 8; ++j) {
            const int k = kt * 32 + kg * 8 + j;
            const int m = mt * 16 + l15;
            int idx = k - m + 1;                 // w-index + 1
            idx = idx < 0 ? 0 : (idx > 15 ? 15 : idx);
            WV[kt][j] = wtab[idx];
        }

    f32x4 vacc[5];
#pragma unroll
    for (int q = 0; q < 5; ++q) vacc[q] = zero4;
#pragma unroll
    for (int q = 0; q < 5; ++q)
#pragma unroll
        for (int kt = 0; kt < 2; ++kt) {
            const int n = q * 32 + ch * 16 + l15;
            f16x8 sb = *(const f16x8*)(Sh + n * S_PITCH + kt * 32 + kg * 8);
            vacc[q] = __builtin_amdgcn_mfma_f32_16x16x32_f16(
                WV[kt], sb, vacc[q], 0, 0, 0);
        }

    // ---- SSIM epilogue: lane holds 4 pixels, all 5 q's local ----
    const float C1 = 0.0004f, C2 = 0.0036f;
    float lsum = 0.f;
#pragma unroll
    for (int r = 0; r < 4; ++r) {
        const float mux = vacc[0][r], muy = vacc[1][r];
        const float exx = vacc[2][r], eyy = vacc[3][r], exy = vacc[4][r];
        const float mux2 = mux * mux, muy2 = muy * muy, muxy = mux * muy;
        const float sxx = fmaxf(exx - mux2, 0.f);
        const float syy = fmaxf(eyy - muy2, 0.f);
        const float sxy = exy - muxy;
        const float num = (2.f * muxy + C1) * (2.f * sxy + C2);
        const float den = (mux2 + muy2 + C1) * (sxx + syy + C2);
        lsum += num * __builtin_amdgcn_rcpf(den);
    }

#pragma unroll
    for (int off = 32; off > 0; off >>= 1)
        lsum += __shfl_down(lsum, off, 64);
    if (lane == 0) red[w] = lsum;
    __syncthreads();
    if (tid == 0)
        partial[blockIdx.x] = red[0] + red[1] + red[2] + red[3];
}

__global__ void ssim_final(const float* __restrict__ partial,
                           float* __restrict__ out)
{
    const int tid = threadIdx.x;
    double s = 0.0;
    for (int i = tid; i < NBLOCKS; i += 256) s += (double)partial[i];
#pragma unroll
    for (int off = 32; off > 0; off >>= 1)
        s += __shfl_down(s, off, 64);
    __shared__ double ws[4];
    if ((tid & 63) == 0) ws[tid >> 6] = s;
    __syncthreads();
    if (tid == 0) {
        const double tot = ws[0] + ws[1] + ws[2] + ws[3];
        out[0] = (float)(1.0 - tot / (double)NPIX);
    }
}

extern "C" void kernel_launch(void* const* d_in, const int* in_sizes, int n_in,
                              void* d_out, int out_size, void* d_ws, size_t ws_size,
                              hipStream_t stream)
{
    const float* x = (const float*)d_in[0];   // pred
    const float* y = (const float*)d_in[1];   // target
    float* partial = (float*)d_ws;            // NBLOCKS*4 = 49,152 B
    float* out = (float*)d_out;

    ssim_main<<<NBLOCKS, 256, 0, stream>>>(x, y, partial);
    ssim_final<<<1, 256, 0, stream>>>(partial, out);
}

// Round 6
// 68.248 us; speedup vs baseline: 1.7600x; 1.7600x over previous
//
#include <hip/hip_runtime.h>
#include <math.h>

// SSIM loss, round 6 = round 5 with the cvt_pkrtz type mismatch fixed
// (builtin returns __fp16x2; bit-cast to our _Float16x2 via pkrtz()).
//  - TH=22 (IH=32): phase-1 = 512 4-wide units = exactly 2/thread (uniform).
//  - h-blur via v_dot2_f32_f16 (packed pair dot, f32 accumulate).
//  - LDS 21.1 KB -> 6 blocks/CU with __launch_bounds__(256,6).
//  - bijective XCD swizzle (9216 % 8 == 0).

typedef _Float16 h2 __attribute__((ext_vector_type(2)));

#define TH 22
#define IH 32               // TH + 10
#define ROWA 132            // u32 words per aA row (32 colpairs * 4 q + 4 pad)
#define ROWB 33             // u32 words per aB row
#define NPIX (16 * 3 * 512 * 512)
#define NRT 24              // row tiles: 24*22 = 528 >= 512 (tail masked)
#define NBLOCKS (48 * NRT * 8)   // 9216

static __device__ __forceinline__ unsigned h2u(h2 v) {
    union { h2 h; unsigned u; } x; x.h = v; return x.u;
}
static __device__ __forceinline__ h2 u2h(unsigned u) {
    union { unsigned u; h2 h; } x; x.u = u; return x.h;
}
static __device__ __forceinline__ h2 pkrtz(float a, float b) {
    auto r = __builtin_amdgcn_cvt_pkrtz(a, b);   // __fp16x2
    union { decltype(r) f; h2 h; } x; x.f = r; return x.h;
}
static __device__ __forceinline__ float fdot2f(h2 a, h2 b, float c) {
#if __has_builtin(__builtin_amdgcn_fdot2)
    return __builtin_amdgcn_fdot2(a, b, c, false);
#else
    return c + (float)a[0] * (float)b[0] + (float)a[1] * (float)b[1];
#endif
}

__global__ __launch_bounds__(256, 6) void ssim_main(
    const float* __restrict__ X, const float* __restrict__ Y,
    float* __restrict__ partial)
{
    static const float GWF[11] = {
        0.00102838f, 0.00759876f, 0.03600026f, 0.10936083f, 0.21300567f,
        0.26601190f, 0.21300567f, 0.10936083f, 0.03600026f, 0.00759876f,
        0.00102838f};

    // weight pairs for dot2: pair T contributes v[2T]*w[d-3] + v[2T+1]*w[d-2],
    // d = 2T - j; WP[d-2] = (gw[d-3], gw[d-2]), OOB -> 0.
    h2 WP[12];
#pragma unroll
    for (int i = 0; i < 12; ++i) {
        const float wlo = (i - 1 >= 0 && i - 1 < 11) ? GWF[i - 1] : 0.f;
        const float whi = (i < 11) ? GWF[i] : 0.f;
        WP[i] = pkrtz(wlo, whi);
    }
    h2 WV2[11];
#pragma unroll
    for (int k = 0; k < 11; ++k)
        WV2[k] = pkrtz(GWF[k], GWF[k]);

    __shared__ __align__(16) unsigned aA[IH * ROWA];  // 16,896 B
    __shared__ __align__(16) unsigned aB[IH * ROWB];  //  4,224 B
    __shared__ float red[4];

    const int tid = threadIdx.x;
    const int bid = blockIdx.x;

    // bijective XCD swizzle: each XCD gets 1152 consecutive tiles (6 planes)
    const int wg    = (bid & 7) * (NBLOCKS / 8) + (bid >> 3);
    const int plane = wg / (NRT * 8);
    const int tt    = wg - plane * (NRT * 8);
    const int tr    = tt >> 3;          // 0..23
    const int tc    = tt & 7;           // 0..7

    const float* xp = X + (size_t)plane * (512 * 512);
    const float* yp = Y + (size_t)plane * (512 * 512);
    const int row0 = tr * TH - 5;       // global row of aA row 0
    const int colT = tc * 64;           // global col of output col 0

    // ---------------- Phase 1: horizontal blur (dot2, f32 acc) -------------
    // unit = (r in [0,32)) x (g4 in [0,16)): 4 output cols; 2 units/thread.
#pragma unroll
    for (int pass = 0; pass < 2; ++pass) {
        const int u  = tid + pass * 256;
        const int r  = u >> 4;          // 0..31
        const int g4 = u & 15;
        const int gr = row0 + r;
        const bool rok = ((unsigned)gr < 512u);
        const float* xr = xp + gr * 512;
        const float* yr = yp + gr * 512;
        const int al0 = colT + g4 * 4 - 8;   // aligned window start (mult of 4)

        h2 xq[10], yq[10];              // input pairs T=0..9 (use 1..8)
#pragma unroll
        for (int t = 0; t < 5; ++t) {
            const int ac = al0 + 4 * t;
            const bool ok = rok && (ac >= 0) && (ac <= 508);
            float4 xv = make_float4(0.f, 0.f, 0.f, 0.f), yv = xv;
            if (ok) { xv = *(const float4*)(xr + ac); yv = *(const float4*)(yr + ac); }
            xq[2 * t]     = pkrtz(xv.x, xv.y);
            xq[2 * t + 1] = pkrtz(xv.z, xv.w);
            yq[2 * t]     = pkrtz(yv.x, yv.y);
            yq[2 * t + 1] = pkrtz(yv.z, yv.w);
        }

        float s0[4], s1[4], s2[4], s3[4], s4[4];
#pragma unroll
        for (int j = 0; j < 4; ++j) { s0[j]=0.f; s1[j]=0.f; s2[j]=0.f; s3[j]=0.f; s4[j]=0.f; }

#pragma unroll
        for (int T = 1; T <= 8; ++T) {
            const h2 xa = xq[T], ya = yq[T];
            const h2 xx = xa * xa, yy = ya * ya, xy = xa * ya;
#pragma unroll
            for (int j = 0; j < 4; ++j) {
                const int d = 2 * T - j;           // compile-time
                if (d >= 2 && d <= 13) {
                    const h2 W = WP[d - 2];
                    s0[j] = fdot2f(xa, W, s0[j]);
                    s1[j] = fdot2f(ya, W, s1[j]);
                    s2[j] = fdot2f(xx, W, s2[j]);
                    s3[j] = fdot2f(yy, W, s3[j]);
                    s4[j] = fdot2f(xy, W, s4[j]);
                }
            }
        }

        // store: aA[r][colpair][q0..3] as uint4, aB[r][colpair] = q4
        unsigned* wa = aA + r * ROWA + g4 * 8;
        unsigned* wb = aB + r * ROWB + g4 * 2;
#pragma unroll
        for (int t2 = 0; t2 < 2; ++t2) {
            uint4 W4;
            W4.x = h2u(pkrtz(s0[2*t2], s0[2*t2+1]));
            W4.y = h2u(pkrtz(s1[2*t2], s1[2*t2+1]));
            W4.z = h2u(pkrtz(s2[2*t2], s2[2*t2+1]));
            W4.w = h2u(pkrtz(s3[2*t2], s3[2*t2+1]));
            *(uint4*)(wa + 4 * t2) = W4;
            wb[t2] = h2u(pkrtz(s4[2*t2], s4[2*t2+1]));
        }
    }
    __syncthreads();

    // ---------------- Phase 2: vertical blur (packed col pairs) -------------
    // thread = (cp in [0,32)) x (g2 in [0,8)); g2 owns rows rb..rb+2 (g2=7: 1)
    const int cp = tid & 31;
    const int g2 = tid >> 5;
    const int rb = g2 * 3;              // 0,3,..,21

    h2 m0[3], m1[3], m2[3], m3[3], m4[3];
#pragma unroll
    for (int j = 0; j < 3; ++j) {
        m0[j] = u2h(0u); m1[j] = u2h(0u); m2[j] = u2h(0u);
        m3[j] = u2h(0u); m4[j] = u2h(0u);
    }

#pragma unroll
    for (int rr = 0; rr < 13; ++rr) {
        const int row = (rb + rr < IH) ? (rb + rr) : (IH - 1);  // clamp: junk->masked j
        const uint4 w4 = *(const uint4*)(aA + row * ROWA + cp * 4);
        const unsigned wb = aB[row * ROWB + cp];
        const h2 q0 = u2h(w4.x), q1 = u2h(w4.y);
        const h2 q2 = u2h(w4.z), q3 = u2h(w4.w), q4 = u2h(wb);
#pragma unroll
        for (int j = 0; j < 3; ++j) {
            const int k = rr - j;                  // compile-time
            if (k >= 0 && k < 11) {
                const h2 w = WV2[k];
                m0[j] = w * q0 + m0[j];
                m1[j] = w * q1 + m1[j];
                m2[j] = w * q2 + m2[j];
                m3[j] = w * q3 + m3[j];
                m4[j] = w * q4 + m4[j];
            }
        }
    }

    // ---------------- SSIM map + reduction ----------------
    const float C1 = 0.0004f, C2 = 0.0036f;
    float lsum = 0.f;
#pragma unroll
    for (int j = 0; j < 3; ++j) {
        const int o = rb + j;                       // tile-local output row
        const bool valid = (o < TH) && (tr * TH + o < 512);
        float acc = 0.f;
#pragma unroll
        for (int hh = 0; hh < 2; ++hh) {
            const float mux = (float)m0[j][hh];
            const float muy = (float)m1[j][hh];
            const float exx = (float)m2[j][hh];
            const float eyy = (float)m3[j][hh];
            const float exy = (float)m4[j][hh];
            const float mux2 = mux * mux, muy2 = muy * muy, muxy = mux * muy;
            const float sxx = fmaxf(exx - mux2, 0.f);
            const float syy = fmaxf(eyy - muy2, 0.f);
            const float sxy = exy - muxy;
            const float num = (2.f * muxy + C1) * (2.f * sxy + C2);
            const float den = (mux2 + muy2 + C1) * (sxx + syy + C2);
            acc += num * __builtin_amdgcn_rcpf(den);
        }
        lsum += valid ? acc : 0.f;
    }

#pragma unroll
    for (int off = 32; off > 0; off >>= 1)
        lsum += __shfl_down(lsum, off, 64);
    if ((tid & 63) == 0) red[tid >> 6] = lsum;
    __syncthreads();
    if (tid == 0)
        partial[bid] = red[0] + red[1] + red[2] + red[3];
}

__global__ void ssim_final(const float* __restrict__ partial,
                           float* __restrict__ out)
{
    const int tid = threadIdx.x;
    double s = 0.0;
    for (int i = tid; i < NBLOCKS; i += 256) s += (double)partial[i];
#pragma unroll
    for (int off = 32; off > 0; off >>= 1)
        s += __shfl_down(s, off, 64);
    __shared__ double ws[4];
    if ((tid & 63) == 0) ws[tid >> 6] = s;
    __syncthreads();
    if (tid == 0) {
        const double tot = ws[0] + ws[1] + ws[2] + ws[3];
        out[0] = (float)(1.0 - tot / (double)NPIX);
    }
}

extern "C" void kernel_launch(void* const* d_in, const int* in_sizes, int n_in,
                              void* d_out, int out_size, void* d_ws, size_t ws_size,
                              hipStream_t stream)
{
    const float* x = (const float*)d_in[0];   // pred
    const float* y = (const float*)d_in[1];   // target
    float* partial = (float*)d_ws;            // NBLOCKS*4 = 36,864 B
    float* out = (float*)d_out;

    ssim_main<<<NBLOCKS, 256, 0, stream>>>(x, y, partial);
    ssim_final<<<1, 256, 0, stream>>>(partial, out);
}

// Round 7
// 56.678 us; speedup vs baseline: 2.1192x; 1.2041x over previous
//
#include <hip/hip_runtime.h>
#include <math.h>

// SSIM loss, round 7. r6 was VALU-issue-bound (VALUBusy 83%). Changes:
//  - 4 blurred quantities instead of 5: blur(x), blur(y), blur(x^2+y^2),
//    blur(xy). den needs only sigma_x^2+sigma_y^2 = blur(x2+y2)-mux^2-muy^2.
//    (ref clamps each variance at 0 separately; true variances ~1 here and
//    rounding negatives are ~1e-7 -> far under the 2e-2 threshold.)
//    -20% blur FMAs both passes; aB array gone; LDS 21.1 -> 16.9 KB.
//  - 8-col phase-1 units: exactly 256 units = 1/thread (no loop, uniform),
//    halves per-unit fixed costs (pkrtz-in 40->20, muls 48->30, 1 addr chain).
//  - rest unchanged from r6: dot2 h-blur f32-acc, packed f16 v-blur,
//    bijective XCD swizzle, masked epilogue, deterministic 2-level reduce.

typedef _Float16 h2 __attribute__((ext_vector_type(2)));

#define TH 22
#define IH 32               // TH + 10
#define ROWA 132            // u32 words per aA row: 32 colpairs * 4 q + 4 pad
#define NPIX (16 * 3 * 512 * 512)
#define NRT 24              // row tiles: 24*22 = 528 >= 512 (tail masked)
#define NBLOCKS (48 * NRT * 8)   // 9216; % 8 == 0 -> bijective XCD swizzle

static __device__ __forceinline__ unsigned h2u(h2 v) {
    union { h2 h; unsigned u; } x; x.h = v; return x.u;
}
static __device__ __forceinline__ h2 u2h(unsigned u) {
    union { unsigned u; h2 h; } x; x.u = u; return x.h;
}
static __device__ __forceinline__ h2 pkrtz(float a, float b) {
    auto r = __builtin_amdgcn_cvt_pkrtz(a, b);
    union { decltype(r) f; h2 h; } x; x.f = r; return x.h;
}
static __device__ __forceinline__ float fdot2f(h2 a, h2 b, float c) {
#if __has_builtin(__builtin_amdgcn_fdot2)
    return __builtin_amdgcn_fdot2(a, b, c, false);
#else
    return c + (float)a[0] * (float)b[0] + (float)a[1] * (float)b[1];
#endif
}

__global__ __launch_bounds__(256, 6) void ssim_main(
    const float* __restrict__ X, const float* __restrict__ Y,
    float* __restrict__ partial)
{
    static const float GWF[11] = {
        0.00102838f, 0.00759876f, 0.03600026f, 0.10936083f, 0.21300567f,
        0.26601190f, 0.21300567f, 0.10936083f, 0.03600026f, 0.00759876f,
        0.00102838f};

    // dot2 weight pairs: pair T (rel cols 2T-8, 2T-7) hits output col j with
    // WP[d-2] = (w[d-3], w[d-2]), d = 2T - j, valid d in [2,13]; OOB w -> 0.
    h2 WP[12];
#pragma unroll
    for (int i = 0; i < 12; ++i) {
        const float wlo = (i - 1 >= 0 && i - 1 < 11) ? GWF[i - 1] : 0.f;
        const float whi = (i < 11) ? GWF[i] : 0.f;
        WP[i] = pkrtz(wlo, whi);
    }
    h2 WV2[11];
#pragma unroll
    for (int k = 0; k < 11; ++k)
        WV2[k] = pkrtz(GWF[k], GWF[k]);

    __shared__ __align__(16) unsigned aA[IH * ROWA];  // 16,896 B
    __shared__ float red[4];

    const int tid = threadIdx.x;
    const int bid = blockIdx.x;

    // bijective XCD swizzle: each XCD gets 1152 consecutive tiles (6 planes)
    const int wg    = (bid & 7) * (NBLOCKS / 8) + (bid >> 3);
    const int plane = wg / (NRT * 8);
    const int tt    = wg - plane * (NRT * 8);
    const int tr    = tt >> 3;          // 0..23
    const int tc    = tt & 7;           // 0..7

    const float* xp = X + (size_t)plane * (512 * 512);
    const float* yp = Y + (size_t)plane * (512 * 512);
    const int row0 = tr * TH - 5;       // global row of aA row 0
    const int colT = tc * 64;           // global col of output col 0

    // ---------------- Phase 1: horizontal blur, 8 cols/thread --------------
    {
        const int r  = tid >> 3;        // 0..31
        const int g8 = tid & 7;         // 8-col group
        const int gr = row0 + r;
        const bool rok = ((unsigned)gr < 512u);
        const float* xr = xp + gr * 512;
        const float* yr = yp + gr * 512;
        const int al0 = colT + g8 * 8 - 8;   // aligned window start

        h2 xq[11], yq[11];              // pairs 1..10 used
#pragma unroll
        for (int t = 0; t < 6; ++t) {
            const int ac = al0 + 4 * t;
            const bool ok = rok && (ac >= 0) && (ac <= 508);
            float4 xv = make_float4(0.f, 0.f, 0.f, 0.f), yv = xv;
            if (ok) { xv = *(const float4*)(xr + ac); yv = *(const float4*)(yr + ac); }
            const int p0 = 2 * t, p1 = 2 * t + 1;
            if (p0 >= 1 && p0 <= 10) { xq[p0] = pkrtz(xv.x, xv.y); yq[p0] = pkrtz(yv.x, yv.y); }
            if (p1 >= 1 && p1 <= 10) { xq[p1] = pkrtz(xv.z, xv.w); yq[p1] = pkrtz(yv.z, yv.w); }
        }

        float s0[8], s1[8], s2[8], s3[8];
#pragma unroll
        for (int j = 0; j < 8; ++j) { s0[j]=0.f; s1[j]=0.f; s2[j]=0.f; s3[j]=0.f; }

#pragma unroll
        for (int T = 1; T <= 10; ++T) {
            const h2 xa = xq[T], ya = yq[T];
            const h2 xy = xa * ya;
            const h2 ss = ya * ya + xa * xa;     // pk_mul + pk_fma
#pragma unroll
            for (int j = 0; j < 8; ++j) {
                const int d = 2 * T - j;         // compile-time
                if (d >= 2 && d <= 13) {
                    const h2 W = WP[d - 2];
                    s0[j] = fdot2f(xa, W, s0[j]);
                    s1[j] = fdot2f(ya, W, s1[j]);
                    s2[j] = fdot2f(ss, W, s2[j]);
                    s3[j] = fdot2f(xy, W, s3[j]);
                }
            }
        }

        // store: aA[r][colpair = g8*4 + t2] = {q0,q1,q2,q3} packed
        unsigned* wa = aA + r * ROWA + g8 * 16;
#pragma unroll
        for (int t2 = 0; t2 < 4; ++t2) {
            uint4 W4;
            W4.x = h2u(pkrtz(s0[2*t2], s0[2*t2+1]));
            W4.y = h2u(pkrtz(s1[2*t2], s1[2*t2+1]));
            W4.z = h2u(pkrtz(s2[2*t2], s2[2*t2+1]));
            W4.w = h2u(pkrtz(s3[2*t2], s3[2*t2+1]));
            *(uint4*)(wa + 4 * t2) = W4;
        }
    }
    __syncthreads();

    // ---------------- Phase 2: vertical blur (packed col pairs) -------------
    const int cp = tid & 31;
    const int g2 = tid >> 5;
    const int rb = g2 * 3;              // 0,3,..,21

    h2 m0[3], m1[3], m2[3], m3[3];
#pragma unroll
    for (int j = 0; j < 3; ++j) {
        m0[j] = u2h(0u); m1[j] = u2h(0u); m2[j] = u2h(0u); m3[j] = u2h(0u);
    }

#pragma unroll
    for (int rr = 0; rr < 13; ++rr) {
        const int row = (rb + rr < IH) ? (rb + rr) : (IH - 1);  // junk -> masked j
        const uint4 w4 = *(const uint4*)(aA + row * ROWA + cp * 4);
        const h2 q0 = u2h(w4.x), q1 = u2h(w4.y);
        const h2 q2 = u2h(w4.z), q3 = u2h(w4.w);
#pragma unroll
        for (int j = 0; j < 3; ++j) {
            const int k = rr - j;                  // compile-time
            if (k >= 0 && k < 11) {
                const h2 w = WV2[k];
                m0[j] = w * q0 + m0[j];
                m1[j] = w * q1 + m1[j];
                m2[j] = w * q2 + m2[j];
                m3[j] = w * q3 + m3[j];
            }
        }
    }

    // ---------------- SSIM map + reduction ----------------
    const float C1 = 0.0004f, C2 = 0.0036f;
    float lsum = 0.f;
#pragma unroll
    for (int j = 0; j < 3; ++j) {
        const int o = rb + j;                       // tile-local output row
        const bool valid = (o < TH) && (tr * TH + o < 512);
        float acc = 0.f;
#pragma unroll
        for (int hh = 0; hh < 2; ++hh) {
            const float mux = (float)m0[j][hh];
            const float muy = (float)m1[j][hh];
            const float ess = (float)m2[j][hh];    // blur(x^2+y^2)
            const float exy = (float)m3[j][hh];
            const float mux2 = mux * mux, muy2 = muy * muy, muxy = mux * muy;
            const float svar = fmaxf(ess - mux2 - muy2, 0.f);  // sxx+syy
            const float sxy = exy - muxy;
            const float num = (2.f * muxy + C1) * (2.f * sxy + C2);
            const float den = (mux2 + muy2 + C1) * (svar + C2);
            acc += num * __builtin_amdgcn_rcpf(den);
        }
        lsum += valid ? acc : 0.f;
    }

#pragma unroll
    for (int off = 32; off > 0; off >>= 1)
        lsum += __shfl_down(lsum, off, 64);
    if ((tid & 63) == 0) red[tid >> 6] = lsum;
    __syncthreads();
    if (tid == 0)
        partial[bid] = red[0] + red[1] + red[2] + red[3];
}

__global__ void ssim_final(const float* __restrict__ partial,
                           float* __restrict__ out)
{
    const int tid = threadIdx.x;
    double s = 0.0;
    for (int i = tid; i < NBLOCKS; i += 256) s += (double)partial[i];
#pragma unroll
    for (int off = 32; off > 0; off >>= 1)
        s += __shfl_down(s, off, 64);
    __shared__ double ws[4];
    if ((tid & 63) == 0) ws[tid >> 6] = s;
    __syncthreads();
    if (tid == 0) {
        const double tot = ws[0] + ws[1] + ws[2] + ws[3];
        out[0] = (float)(1.0 - tot / (double)NPIX);
    }
}

extern "C" void kernel_launch(void* const* d_in, const int* in_sizes, int n_in,
                              void* d_out, int out_size, void* d_ws, size_t ws_size,
                              hipStream_t stream)
{
    const float* x = (const float*)d_in[0];   // pred
    const float* y = (const float*)d_in[1];   // target
    float* partial = (float*)d_ws;            // NBLOCKS*4 = 36,864 B
    float* out = (float*)d_out;

    ssim_main<<<NBLOCKS, 256, 0, stream>>>(x, y, partial);
    ssim_final<<<1, 256, 0, stream>>>(partial, out);
}

// Round 8
// 48.932 us; speedup vs baseline: 2.4547x; 1.1583x over previous
//
#include <hip/hip_runtime.h>
#include <math.h>

// SSIM loss, round 8. Same instruction structure as r7 (dot2 h-blur f32-acc,
// packed-f16 v-blur, 4 quantities, XCD swizzle). Geometry change only:
//   TH=54, IH=64  (r7: 22/32)
//   - phase-1 halo redundancy 1.45x -> 1.19x (-18% of dominant phase)
//   - phase-2 LDS reads per output row 4.33 -> 2.43 (-44%)
//   - phase-1 = 512 units = exactly 2/thread (still uniform)
//   - LDS 33.8 KB -> 4 blocks/CU (16 waves); acceptable: kernel is
//     issue-bound (VALUBusy 71%), not latency-bound.

typedef _Float16 h2 __attribute__((ext_vector_type(2)));

#define TH 54
#define IH 64               // TH + 10
#define ROWA 132            // u32 words per aA row: 32 colpairs * 4 q + 4 pad
#define NPIX (16 * 3 * 512 * 512)
#define NRT 10              // row tiles: 10*54 = 540 >= 512 (tail masked)
#define NBLOCKS (48 * NRT * 8)   // 3840; % 8 == 0 -> bijective XCD swizzle

static __device__ __forceinline__ unsigned h2u(h2 v) {
    union { h2 h; unsigned u; } x; x.h = v; return x.u;
}
static __device__ __forceinline__ h2 u2h(unsigned u) {
    union { unsigned u; h2 h; } x; x.u = u; return x.h;
}
static __device__ __forceinline__ h2 pkrtz(float a, float b) {
    auto r = __builtin_amdgcn_cvt_pkrtz(a, b);
    union { decltype(r) f; h2 h; } x; x.f = r; return x.h;
}
static __device__ __forceinline__ float fdot2f(h2 a, h2 b, float c) {
#if __has_builtin(__builtin_amdgcn_fdot2)
    return __builtin_amdgcn_fdot2(a, b, c, false);
#else
    return c + (float)a[0] * (float)b[0] + (float)a[1] * (float)b[1];
#endif
}

__global__ __launch_bounds__(256, 4) void ssim_main(
    const float* __restrict__ X, const float* __restrict__ Y,
    float* __restrict__ partial)
{
    static const float GWF[11] = {
        0.00102838f, 0.00759876f, 0.03600026f, 0.10936083f, 0.21300567f,
        0.26601190f, 0.21300567f, 0.10936083f, 0.03600026f, 0.00759876f,
        0.00102838f};

    // dot2 weight pairs: pair T (rel cols 2T-8, 2T-7) hits output col j with
    // WP[d-2] = (w[d-3], w[d-2]), d = 2T - j, valid d in [2,13]; OOB w -> 0.
    h2 WP[12];
#pragma unroll
    for (int i = 0; i < 12; ++i) {
        const float wlo = (i - 1 >= 0 && i - 1 < 11) ? GWF[i - 1] : 0.f;
        const float whi = (i < 11) ? GWF[i] : 0.f;
        WP[i] = pkrtz(wlo, whi);
    }
    h2 WV2[11];
#pragma unroll
    for (int k = 0; k < 11; ++k)
        WV2[k] = pkrtz(GWF[k], GWF[k]);

    __shared__ __align__(16) unsigned aA[IH * ROWA];  // 33,792 B
    __shared__ float red[4];

    const int tid = threadIdx.x;
    const int bid = blockIdx.x;

    // bijective XCD swizzle: each XCD gets NBLOCKS/8 consecutive tiles
    const int wg    = (bid & 7) * (NBLOCKS / 8) + (bid >> 3);
    const int plane = wg / (NRT * 8);
    const int tt    = wg - plane * (NRT * 8);
    const int tr    = tt >> 3;          // 0..9
    const int tc    = tt & 7;           // 0..7

    const float* xp = X + (size_t)plane * (512 * 512);
    const float* yp = Y + (size_t)plane * (512 * 512);
    const int row0 = tr * TH - 5;       // global row of aA row 0
    const int colT = tc * 64;           // global col of output col 0

    // ---------------- Phase 1: horizontal blur, 8 cols/unit, 2 units/thread -
#pragma unroll
    for (int pass = 0; pass < 2; ++pass) {
        const int u  = tid + pass * 256;
        const int r  = u >> 3;          // 0..63
        const int g8 = u & 7;           // 8-col group
        const int gr = row0 + r;
        const bool rok = ((unsigned)gr < 512u);
        const float* xr = xp + gr * 512;
        const float* yr = yp + gr * 512;
        const int al0 = colT + g8 * 8 - 8;   // aligned window start

        h2 xq[11], yq[11];              // pairs 1..10 used
#pragma unroll
        for (int t = 0; t < 6; ++t) {
            const int ac = al0 + 4 * t;
            const bool ok = rok && (ac >= 0) && (ac <= 508);
            float4 xv = make_float4(0.f, 0.f, 0.f, 0.f), yv = xv;
            if (ok) { xv = *(const float4*)(xr + ac); yv = *(const float4*)(yr + ac); }
            const int p0 = 2 * t, p1 = 2 * t + 1;
            if (p0 >= 1 && p0 <= 10) { xq[p0] = pkrtz(xv.x, xv.y); yq[p0] = pkrtz(yv.x, yv.y); }
            if (p1 >= 1 && p1 <= 10) { xq[p1] = pkrtz(xv.z, xv.w); yq[p1] = pkrtz(yv.z, yv.w); }
        }

        float s0[8], s1[8], s2[8], s3[8];
#pragma unroll
        for (int j = 0; j < 8; ++j) { s0[j]=0.f; s1[j]=0.f; s2[j]=0.f; s3[j]=0.f; }

#pragma unroll
        for (int T = 1; T <= 10; ++T) {
            const h2 xa = xq[T], ya = yq[T];
            const h2 xy = xa * ya;
            const h2 ss = ya * ya + xa * xa;     // pk_mul + pk_fma
#pragma unroll
            for (int j = 0; j < 8; ++j) {
                const int d = 2 * T - j;         // compile-time
                if (d >= 2 && d <= 13) {
                    const h2 W = WP[d - 2];
                    s0[j] = fdot2f(xa, W, s0[j]);
                    s1[j] = fdot2f(ya, W, s1[j]);
                    s2[j] = fdot2f(ss, W, s2[j]);
                    s3[j] = fdot2f(xy, W, s3[j]);
                }
            }
        }

        // store: aA[r][colpair = g8*4 + t2] = {q0,q1,q2,q3} packed
        unsigned* wa = aA + r * ROWA + g8 * 16;
#pragma unroll
        for (int t2 = 0; t2 < 4; ++t2) {
            uint4 W4;
            W4.x = h2u(pkrtz(s0[2*t2], s0[2*t2+1]));
            W4.y = h2u(pkrtz(s1[2*t2], s1[2*t2+1]));
            W4.z = h2u(pkrtz(s2[2*t2], s2[2*t2+1]));
            W4.w = h2u(pkrtz(s3[2*t2], s3[2*t2+1]));
            *(uint4*)(wa + 4 * t2) = W4;
        }
    }
    __syncthreads();

    // ---------------- Phase 2: vertical blur (packed col pairs) -------------
    // thread = (cp in [0,32)) x (g2 in [0,8)); g2 owns rows rb..rb+6
    const int cp = tid & 31;
    const int g2 = tid >> 5;
    const int rb = g2 * 7;              // 0,7,..,49 (rows 54,55 masked)

    h2 m0[7], m1[7], m2[7], m3[7];
#pragma unroll
    for (int j = 0; j < 7; ++j) {
        m0[j] = u2h(0u); m1[j] = u2h(0u); m2[j] = u2h(0u); m3[j] = u2h(0u);
    }

#pragma unroll
    for (int rr = 0; rr < 17; ++rr) {
        const int row = (rb + rr < IH) ? (rb + rr) : (IH - 1);  // junk -> masked j
        const uint4 w4 = *(const uint4*)(aA + row * ROWA + cp * 4);
        const h2 q0 = u2h(w4.x), q1 = u2h(w4.y);
        const h2 q2 = u2h(w4.z), q3 = u2h(w4.w);
#pragma unroll
        for (int j = 0; j < 7; ++j) {
            const int k = rr - j;                  // compile-time
            if (k >= 0 && k < 11) {
                const h2 w = WV2[k];
                m0[j] = w * q0 + m0[j];
                m1[j] = w * q1 + m1[j];
                m2[j] = w * q2 + m2[j];
                m3[j] = w * q3 + m3[j];
            }
        }
    }

    // ---------------- SSIM map + reduction ----------------
    const float C1 = 0.0004f, C2 = 0.0036f;
    float lsum = 0.f;
#pragma unroll
    for (int j = 0; j < 7; ++j) {
        const int o = rb + j;                       // tile-local output row
        const bool valid = (o < TH) && (tr * TH + o < 512);
        float acc = 0.f;
#pragma unroll
        for (int hh = 0; hh < 2; ++hh) {
            const float mux = (float)m0[j][hh];
            const float muy = (float)m1[j][hh];
            const float ess = (float)m2[j][hh];    // blur(x^2+y^2)
            const float exy = (float)m3[j][hh];
            const float mux2 = mux * mux, muy2 = muy * muy, muxy = mux * muy;
            const float svar = fmaxf(ess - mux2 - muy2, 0.f);  // sxx+syy
            const float sxy = exy - muxy;
            const float num = (2.f * muxy + C1) * (2.f * sxy + C2);
            const float den = (mux2 + muy2 + C1) * (svar + C2);
            acc += num * __builtin_amdgcn_rcpf(den);
        }
        lsum += valid ? acc : 0.f;
    }

#pragma unroll
    for (int off = 32; off > 0; off >>= 1)
        lsum += __shfl_down(lsum, off, 64);
    if ((tid & 63) == 0) red[tid >> 6] = lsum;
    __syncthreads();
    if (tid == 0)
        partial[bid] = red[0] + red[1] + red[2] + red[3];
}

__global__ void ssim_final(const float* __restrict__ partial,
                           float* __restrict__ out)
{
    const int tid = threadIdx.x;
    double s = 0.0;
    for (int i = tid; i < NBLOCKS; i += 256) s += (double)partial[i];
#pragma unroll
    for (int off = 32; off > 0; off >>= 1)
        s += __shfl_down(s, off, 64);
    __shared__ double ws[4];
    if ((tid & 63) == 0) ws[tid >> 6] = s;
    __syncthreads();
    if (tid == 0) {
        const double tot = ws[0] + ws[1] + ws[2] + ws[3];
        out[0] = (float)(1.0 - tot / (double)NPIX);
    }
}

extern "C" void kernel_launch(void* const* d_in, const int* in_sizes, int n_in,
                              void* d_out, int out_size, void* d_ws, size_t ws_size,
                              hipStream_t stream)
{
    const float* x = (const float*)d_in[0];   // pred
    const float* y = (const float*)d_in[1];   // target
    float* partial = (float*)d_ws;            // NBLOCKS*4 = 15,360 B
    float* out = (float*)d_out;

    ssim_main<<<NBLOCKS, 256, 0, stream>>>(x, y, partial);
    ssim_final<<<1, 256, 0, stream>>>(partial, out);
}